// Round 17
// baseline (124.051 us; speedup 1.0000x reference)
//
#include <hip/hip_runtime.h>
#include <hip/hip_bf16.h>

#define GAT_N 8192
#define GAT_K 256
#define GAT_D 64
#define GAT_ALPHA 0.2f
#define GAT_FILL 1e-15f

typedef float f32x4 __attribute__((ext_vector_type(4)));
typedef short bf16x8 __attribute__((ext_vector_type(8)));

static __device__ __forceinline__ unsigned f2bf_u(float x) {
  unsigned u = __float_as_uint(x);
  u += 0x7FFFu + ((u >> 16) & 1u);
  return u >> 16;
}

static __device__ __forceinline__ float rfl(float x) {
  return __uint_as_float(__builtin_amdgcn_readfirstlane(__float_as_uint(x)));
}

// ---------------------------------------------------------------------------
// Kernel 1: register-tiled Wh = h @ W; emits WhT_f in MFMA-fragment-tiled
// layout (validated round 15/16).
// ---------------------------------------------------------------------------
__global__ __launch_bounds__(256) void k_prep(const float* __restrict__ h,
                                              const float* __restrict__ W,
                                              const float* __restrict__ av,
                                              float* __restrict__ s_src,
                                              float* __restrict__ s_dst,
                                              short* __restrict__ WhT_f,
                                              float* __restrict__ bmax) {
  __shared__ short T[4][64][8];
  __shared__ float wmLds[4];
  const int tid = threadIdx.x;
  const int wv = tid >> 6, lane = tid & 63;
  const int r0 = blockIdx.x * 32 + wv * 8;  // 8 consecutive k (=j) indices

  float acc[8], acc2[8];
#pragma unroll
  for (int r = 0; r < 8; ++r) { acc[r] = 0.f; acc2[r] = 0.f; }

  for (int kc = 0; kc < GAT_K; kc += 32) {
    float Wreg[32];
#pragma unroll
    for (int e = 0; e < 32; ++e) Wreg[e] = W[(size_t)(kc + e) * GAT_D + lane];
#pragma unroll
    for (int r = 0; r < 8; ++r) {
      const f32x4* h4 = (const f32x4*)(h + (size_t)(r0 + r) * GAT_K + kc);
#pragma unroll
      for (int q = 0; q < 8; ++q) {
        f32x4 hv = h4[q];
        acc[r] += hv[0] * Wreg[4 * q + 0];
        acc2[r] += hv[1] * Wreg[4 * q + 1];
        acc[r] += hv[2] * Wreg[4 * q + 2];
        acc2[r] += hv[3] * Wreg[4 * q + 3];
      }
    }
  }

  const float a_s = av[lane];
  const float a_d = av[64 + lane];
  float wmax = -3.0e38f;
#pragma unroll
  for (int r = 0; r < 8; ++r) {
    const float accf = acc[r] + acc2[r];
    T[wv][lane][r] = (short)f2bf_u(accf);
    float vs = accf * a_s, vd = accf * a_d;
#pragma unroll
    for (int off = 32; off > 0; off >>= 1) {
      vs += __shfl_xor(vs, off);
      vd += __shfl_xor(vd, off);
    }
    if (lane == 0) { s_src[r0 + r] = vs; s_dst[r0 + r] = vd; }
    wmax = fmaxf(wmax, vd);
  }
  bf16x8 vt = *(const bf16x8*)&T[wv][lane][0];
  {
    const int c = r0 >> 9, f = (r0 & 511) >> 5, kgr = (r0 & 31) >> 3;
    short* dst = WhT_f + (size_t)c * 32768 + (size_t)(lane >> 4) * 8192 +
                 f * 512 + ((lane & 15) + 16 * kgr) * 8;
    *(bf16x8*)dst = vt;
  }

  if (lane == 0) wmLds[wv] = wmax;
  __syncthreads();
  if (tid == 0) {
    bmax[blockIdx.x] = fmaxf(fmaxf(wmLds[0], wmLds[1]), fmaxf(wmLds[2], wmLds[3]));
  }
}

// ---------------------------------------------------------------------------
// Kernel 1b (k_scon): hoist ALL per-row / per-col transcendentals out of
// k_attn. Per row r: scon[r] = {F1, F2, -s, cc} (f32x4). Per col j:
// E1[j] = exp(t_j), E2[j] = exp(alpha*t_j). Same products as before ->
// bit-identical P in k_attn.
// ---------------------------------------------------------------------------
__global__ __launch_bounds__(256) void k_scon(const float* __restrict__ s_src,
                                              const float* __restrict__ s_dst,
                                              const float* __restrict__ bmax,
                                              f32x4* __restrict__ scon,
                                              float* __restrict__ E1,
                                              float* __restrict__ E2) {
  const int r = blockIdx.x * 256 + threadIdx.x;
  const int lane = threadIdx.x & 63;
  float bm = fmaxf(fmaxf(bmax[lane], bmax[lane + 64]),
                   fmaxf(bmax[lane + 128], bmax[lane + 192]));
#pragma unroll
  for (int off = 32; off > 0; off >>= 1) bm = fmaxf(bm, __shfl_xor(bm, off));
  const float tmax = bm;

  const float sc = s_src[r];
  const float x0 = sc + tmax;
  const float m = fmaxf(fmaxf(x0, GAT_ALPHA * x0), GAT_FILL);
  f32x4 s4;
  s4[0] = __expf(sc - m);
  s4[1] = __expf(GAT_ALPHA * sc - m);
  s4[2] = -sc;
  s4[3] = __expf(GAT_FILL - m);
  scon[r] = s4;

  const float t = s_dst[r];
  E1[r] = __expf(t);
  E2[r] = __expf(GAT_ALPHA * t);
}

// ---------------------------------------------------------------------------
// Kernel 2 (k_attn): j-split one-shot blocks (round-16 structure), with
// zero-transcendental prologue (scon/E tables) and launch_bounds(256,4)
// (VGPR cap 128 -> no spills; was (256,6) = cap 85, suspected spilling).
// ---------------------------------------------------------------------------
__global__ __launch_bounds__(256, 4) void k_attn(
    const float* __restrict__ A,
    const float* __restrict__ s_dst,
    const f32x4* __restrict__ scon,
    const float* __restrict__ E1,
    const float* __restrict__ E2,
    const short* __restrict__ WhT_f,
    float* __restrict__ o_part,
    float* __restrict__ l_part) {
  __shared__ char smem[16896];  // P tile [0,16K); reuse: lds_o[4][16][65] | lds_l @16640

  const int tid = threadIdx.x;
  const int wv = tid >> 6, lane = tid & 63;
  const int rsub = lane & 15, kg = lane >> 4;
  const int it = blockIdx.x >> 4, jc = blockIdx.x & 15;
  const int i0 = it * 16, j0 = jc * 512;

  // ---- stage: rows 4wv..4wv+3, two 256-col halves each ----
  const float* Arow = A + (size_t)(i0 + 4 * wv) * GAT_N + j0 + lane * 4;
  const f32x4 t0 = *(const f32x4*)(s_dst + j0 + lane * 4);
  const f32x4 t1 = *(const f32x4*)(s_dst + j0 + 256 + lane * 4);
  const f32x4 E1a = *(const f32x4*)(E1 + j0 + lane * 4);
  const f32x4 E2a = *(const f32x4*)(E2 + j0 + lane * 4);
  const f32x4 E1b = *(const f32x4*)(E1 + j0 + 256 + lane * 4);
  const f32x4 E2b = *(const f32x4*)(E2 + j0 + 256 + lane * 4);

#pragma unroll
  for (int r = 0; r < 4; ++r) {
    const int row = 4 * wv + r;
    f32x4 av0 = *(const f32x4*)(Arow + (size_t)r * GAT_N);
    f32x4 av1 = *(const f32x4*)(Arow + (size_t)r * GAT_N + 256);
    const f32x4 s4 = scon[i0 + row];  // broadcast (same addr all lanes)
    const float F1 = rfl(s4[0]), F2 = rfl(s4[1]);
    const float ns = rfl(s4[2]), cc = rfl(s4[3]);

    float p[4];
#pragma unroll
    for (int e = 0; e < 4; ++e) {
      float psel = (t0[e] >= ns) ? E1a[e] * F1 : E2a[e] * F2;
      p[e] = (av0[e] > 0.f) ? psel : cc;
    }
    __hip_bfloat162 pa = __float22bfloat162_rn(float2{p[0], p[1]});
    __hip_bfloat162 pb = __float22bfloat162_rn(float2{p[2], p[3]});
    uint2 w;
    __builtin_memcpy(&w.x, &pa, 4);
    __builtin_memcpy(&w.y, &pb, 4);
    *(uint2*)(&smem[(row << 10) + ((lane << 3) ^ ((row & 7) << 4))]) = w;

#pragma unroll
    for (int e = 0; e < 4; ++e) {
      float psel = (t1[e] >= ns) ? E1b[e] * F1 : E2b[e] * F2;
      p[e] = (av1[e] > 0.f) ? psel : cc;
    }
    pa = __float22bfloat162_rn(float2{p[0], p[1]});
    pb = __float22bfloat162_rn(float2{p[2], p[3]});
    __builtin_memcpy(&w.x, &pa, 4);
    __builtin_memcpy(&w.y, &pb, 4);
    *(uint2*)(&smem[(row << 10) + ((512 + (lane << 3)) ^ ((row & 7) << 4))]) = w;
  }
  __syncthreads();  // P tile ready

  // ---- MFMA: wave wv owns k-quads 4wv..4wv+3 ----
  bf16x8 ones;
#pragma unroll
  for (int e = 0; e < 8; ++e) ones[e] = (short)0x3F80;

  f32x4 acc0 = {0.f, 0.f, 0.f, 0.f};
  f32x4 acc1 = {0.f, 0.f, 0.f, 0.f};
  f32x4 acc2 = {0.f, 0.f, 0.f, 0.f};
  f32x4 acc3 = {0.f, 0.f, 0.f, 0.f};
  f32x4 accl = {0.f, 0.f, 0.f, 0.f};

  const short* Wb = WhT_f + (size_t)jc * 32768 + lane * 8;
#pragma unroll
  for (int q = 0; q < 4; ++q) {
    const int kq = wv * 4 + q;
    const int raddr = (rsub << 10) + (((kq << 6) | (kg << 4)) ^ ((rsub & 7) << 4));
    bf16x8 bP = *(const bf16x8*)(&smem[raddr]);  // B-op: P[k][n=i]
    bf16x8 a0 = *(const bf16x8*)(Wb + 0 * 8192 + kq * 512);  // A-op: Wh[m=d][k]
    bf16x8 a1 = *(const bf16x8*)(Wb + 1 * 8192 + kq * 512);
    bf16x8 a2 = *(const bf16x8*)(Wb + 2 * 8192 + kq * 512);
    bf16x8 a3 = *(const bf16x8*)(Wb + 3 * 8192 + kq * 512);
    acc0 = __builtin_amdgcn_mfma_f32_16x16x32_bf16(a0, bP, acc0, 0, 0, 0);
    acc1 = __builtin_amdgcn_mfma_f32_16x16x32_bf16(a1, bP, acc1, 0, 0, 0);
    acc2 = __builtin_amdgcn_mfma_f32_16x16x32_bf16(a2, bP, acc2, 0, 0, 0);
    acc3 = __builtin_amdgcn_mfma_f32_16x16x32_bf16(a3, bP, acc3, 0, 0, 0);
    accl = __builtin_amdgcn_mfma_f32_16x16x32_bf16(ones, bP, accl, 0, 0, 0);
  }
  __syncthreads();  // all P reads done before smem reuse

  // ---- combine 4 wave-partials (exact; fixed shift) -> o_part ----
  float* lds_o = (float*)smem;            // [4][16][65]
  float* lds_l = (float*)(smem + 16640);  // [4][16]
#pragma unroll
  for (int r = 0; r < 4; ++r) {
    const int d = kg * 4 + r;
    lds_o[wv * 1040 + rsub * 65 + 0 * 16 + d] = acc0[r];
    lds_o[wv * 1040 + rsub * 65 + 1 * 16 + d] = acc1[r];
    lds_o[wv * 1040 + rsub * 65 + 2 * 16 + d] = acc2[r];
    lds_o[wv * 1040 + rsub * 65 + 3 * 16 + d] = acc3[r];
  }
  if (kg == 0) lds_l[wv * 16 + rsub] = accl[0];
  __syncthreads();

  float* opb = o_part + ((size_t)jc * 512 + it) * 1024;
  for (int idx = tid; idx < 1024; idx += 256) {
    const int ii = idx >> 6, d = idx & 63;
    float o = lds_o[0 * 1040 + ii * 65 + d] + lds_o[1 * 1040 + ii * 65 + d] +
              lds_o[2 * 1040 + ii * 65 + d] + lds_o[3 * 1040 + ii * 65 + d];
    opb[idx] = o;
    if (d == 0) {
      l_part[jc * GAT_N + i0 + ii] = lds_l[0 * 16 + ii] + lds_l[1 * 16 + ii] +
                                     lds_l[2 * 16 + ii] + lds_l[3 * 16 + ii];
    }
  }
}

// ---------------------------------------------------------------------------
// Kernel 3 (k_comb): exact merge of 16 j-chunk partials + ELU.
// ---------------------------------------------------------------------------
__global__ __launch_bounds__(256) void k_comb(const float* __restrict__ o_part,
                                              const float* __restrict__ l_part,
                                              float* __restrict__ out) {
  const int idx = blockIdx.x * 256 + threadIdx.x;  // one f32x4 of out
  const int gi = idx >> 4, d4 = (idx & 15) * 4;
  const int it = gi >> 4, ii = gi & 15;
  f32x4 o = {0.f, 0.f, 0.f, 0.f};
  float l = 0.f;
#pragma unroll
  for (int c = 0; c < 16; ++c) {
    o += *(const f32x4*)(o_part + ((size_t)c * 512 + it) * 1024 + ii * 64 + d4);
    l += l_part[c * GAT_N + gi];
  }
  f32x4 v;
#pragma unroll
  for (int e = 0; e < 4; ++e) {
    float val = o[e] / l;
    v[e] = (val > 0.f) ? val : (__expf(val) - 1.f);
  }
  *(f32x4*)(out + (size_t)gi * GAT_D + d4) = v;
}

// ---------------------------------------------------------------------------
extern "C" void kernel_launch(void* const* d_in, const int* in_sizes, int n_in,
                              void* d_out, int out_size, void* d_ws, size_t ws_size,
                              hipStream_t stream) {
  const float* h = (const float*)d_in[0];
  const float* A = (const float*)d_in[1];
  const float* W = (const float*)d_in[2];
  const float* a = (const float*)d_in[3];
  float* out = (float*)d_out;

  // ws: [0,1K) bmax | [4K,+32K) s_src | [36864,+32K) s_dst | [69632,+1M) WhT_f
  //     [1572864,+512K) l_part | [2097152,+32M) o_part
  //     [35651584,+128K) scon | [35782656,+32K) E1 | [35815424,+32K) E2
  const size_t need = 35815424 + 32768;
  if (ws_size < need) return;
  float* bmax = (float*)d_ws;
  float* s_src = (float*)((char*)d_ws + 4096);
  float* s_dst = (float*)((char*)d_ws + 36864);
  short* WhT_f = (short*)((char*)d_ws + 69632);
  float* l_part = (float*)((char*)d_ws + 1572864);
  float* o_part = (float*)((char*)d_ws + 2097152);
  f32x4* scon = (f32x4*)((char*)d_ws + 35651584);
  float* E1 = (float*)((char*)d_ws + 35782656);
  float* E2 = (float*)((char*)d_ws + 35815424);

  k_prep<<<dim3(256), dim3(256), 0, stream>>>(h, W, a, s_src, s_dst, WhT_f, bmax);
  k_scon<<<dim3(GAT_N / 256), dim3(256), 0, stream>>>(s_src, s_dst, bmax, scon,
                                                      E1, E2);
  k_attn<<<dim3(8192), dim3(256), 0, stream>>>(A, s_dst, scon, E1, E2, WhT_f,
                                               o_part, l_part);
  k_comb<<<dim3(GAT_N * GAT_D / 1024), dim3(256), 0, stream>>>(o_part, l_part, out);
}

// Round 18
// 122.904 us; speedup vs baseline: 1.0093x; 1.0093x over previous
//
#include <hip/hip_runtime.h>
#include <hip/hip_bf16.h>

#define GAT_N 8192
#define GAT_K 256
#define GAT_D 64
#define GAT_ALPHA 0.2f
#define GAT_FILL 1e-15f

typedef float f32x4 __attribute__((ext_vector_type(4)));
typedef short bf16x8 __attribute__((ext_vector_type(8)));

static __device__ __forceinline__ unsigned f2bf_u(float x) {
  unsigned u = __float_as_uint(x);
  u += 0x7FFFu + ((u >> 16) & 1u);
  return u >> 16;
}

static __device__ __forceinline__ float rfl(float x) {
  return __uint_as_float(__builtin_amdgcn_readfirstlane(__float_as_uint(x)));
}

// ---------------------------------------------------------------------------
// Kernel 1: register-tiled Wh = h @ W; emits WhT_f in MFMA-fragment-tiled
// layout (validated rounds 15-17).
// ---------------------------------------------------------------------------
__global__ __launch_bounds__(256) void k_prep(const float* __restrict__ h,
                                              const float* __restrict__ W,
                                              const float* __restrict__ av,
                                              float* __restrict__ s_src,
                                              float* __restrict__ s_dst,
                                              short* __restrict__ WhT_f,
                                              float* __restrict__ bmax) {
  __shared__ short T[4][64][8];
  __shared__ float wmLds[4];
  const int tid = threadIdx.x;
  const int wv = tid >> 6, lane = tid & 63;
  const int r0 = blockIdx.x * 32 + wv * 8;  // 8 consecutive k (=j) indices

  float acc[8], acc2[8];
#pragma unroll
  for (int r = 0; r < 8; ++r) { acc[r] = 0.f; acc2[r] = 0.f; }

  for (int kc = 0; kc < GAT_K; kc += 32) {
    float Wreg[32];
#pragma unroll
    for (int e = 0; e < 32; ++e) Wreg[e] = W[(size_t)(kc + e) * GAT_D + lane];
#pragma unroll
    for (int r = 0; r < 8; ++r) {
      const f32x4* h4 = (const f32x4*)(h + (size_t)(r0 + r) * GAT_K + kc);
#pragma unroll
      for (int q = 0; q < 8; ++q) {
        f32x4 hv = h4[q];
        acc[r] += hv[0] * Wreg[4 * q + 0];
        acc2[r] += hv[1] * Wreg[4 * q + 1];
        acc[r] += hv[2] * Wreg[4 * q + 2];
        acc2[r] += hv[3] * Wreg[4 * q + 3];
      }
    }
  }

  const float a_s = av[lane];
  const float a_d = av[64 + lane];
  float wmax = -3.0e38f;
#pragma unroll
  for (int r = 0; r < 8; ++r) {
    const float accf = acc[r] + acc2[r];
    T[wv][lane][r] = (short)f2bf_u(accf);
    float vs = accf * a_s, vd = accf * a_d;
#pragma unroll
    for (int off = 32; off > 0; off >>= 1) {
      vs += __shfl_xor(vs, off);
      vd += __shfl_xor(vd, off);
    }
    if (lane == 0) { s_src[r0 + r] = vs; s_dst[r0 + r] = vd; }
    wmax = fmaxf(wmax, vd);
  }
  bf16x8 vt = *(const bf16x8*)&T[wv][lane][0];
  {
    const int c = r0 >> 9, f = (r0 & 511) >> 5, kgr = (r0 & 31) >> 3;
    short* dst = WhT_f + (size_t)c * 32768 + (size_t)(lane >> 4) * 8192 +
                 f * 512 + ((lane & 15) + 16 * kgr) * 8;
    *(bf16x8*)dst = vt;
  }

  if (lane == 0) wmLds[wv] = wmax;
  __syncthreads();
  if (tid == 0) {
    bmax[blockIdx.x] = fmaxf(fmaxf(wmLds[0], wmLds[1]), fmaxf(wmLds[2], wmLds[3]));
  }
}

// ---------------------------------------------------------------------------
// Kernel 1b (k_scon): per-row constants only (E tables were a net loss, R17):
//   scon[r] = {F1, F2, -s, cc}
// ---------------------------------------------------------------------------
__global__ __launch_bounds__(256) void k_scon(const float* __restrict__ s_src,
                                              const float* __restrict__ bmax,
                                              f32x4* __restrict__ scon) {
  const int r = blockIdx.x * 256 + threadIdx.x;
  const int lane = threadIdx.x & 63;
  float bm = fmaxf(fmaxf(bmax[lane], bmax[lane + 64]),
                   fmaxf(bmax[lane + 128], bmax[lane + 192]));
#pragma unroll
  for (int off = 32; off > 0; off >>= 1) bm = fmaxf(bm, __shfl_xor(bm, off));
  const float tmax = bm;

  const float sc = s_src[r];
  const float x0 = sc + tmax;
  const float m = fmaxf(fmaxf(x0, GAT_ALPHA * x0), GAT_FILL);
  f32x4 s4;
  s4[0] = __expf(sc - m);
  s4[1] = __expf(GAT_ALPHA * sc - m);
  s4[2] = -sc;
  s4[3] = __expf(GAT_FILL - m);
  scon[r] = s4;
}

// ---------------------------------------------------------------------------
// Kernel 2 (k_attn): BM=64 j-split one-shot blocks — minimal line count.
//   grid = 2048 blocks (it = blk>>4, jc = blk&15), 512 thr (8 waves).
//   Line budget: A 4.2M + WhT_f 2.1M (was 8.4M at BM=16: traffic scales
//   with block count) + o_part 0.6M  ->  ~67us at the measured ~110K
//   lines/us device throughput.
//   Stage: wave wv computes rows 8wv..8wv+7 -> XOR-swizzled LDS P [64][512].
//   MFMA: wave wv owns k-quads {2wv, 2wv+1}; per kq: 4 P-fragments (n) x
//   4 Wh-fragments (dq) -> acc[dq][n], + ones-row-sum accl[n]. 40 MFMA/wave.
//   Epilogue: two-stage LDS combine (waves 0-3 write, 4-7 add, 512-thr sum).
// ---------------------------------------------------------------------------
__global__ __launch_bounds__(512, 4) void k_attn(
    const float* __restrict__ A,
    const float* __restrict__ s_dst,
    const f32x4* __restrict__ scon,
    const short* __restrict__ WhT_f,
    float* __restrict__ o_part,
    float* __restrict__ l_part) {
  __shared__ char smem[67584];  // P tile [0,64K); reuse: lds_o[4][64][65] | lds_l @66560

  const int tid = threadIdx.x;
  const int wv = tid >> 6, lane = tid & 63;
  const int rsub = lane & 15, kg = lane >> 4;
  const int it = blockIdx.x >> 4, jc = blockIdx.x & 15;
  const int i0 = it * 64, j0 = jc * 512;

  // ---- stage: rows 8wv..8wv+7, two 256-col halves each ----
  const float* Arow = A + (size_t)(i0 + 8 * wv) * GAT_N + j0 + lane * 4;
  const f32x4 t0 = *(const f32x4*)(s_dst + j0 + lane * 4);
  const f32x4 t1 = *(const f32x4*)(s_dst + j0 + 256 + lane * 4);

  f32x4 E1a, E2a, E1b, E2b;
#pragma unroll
  for (int e = 0; e < 4; ++e) {
    E1a[e] = __expf(t0[e]);
    E2a[e] = __expf(GAT_ALPHA * t0[e]);
    E1b[e] = __expf(t1[e]);
    E2b[e] = __expf(GAT_ALPHA * t1[e]);
  }

#pragma unroll
  for (int r = 0; r < 8; ++r) {
    const int row = 8 * wv + r;
    f32x4 av0 = *(const f32x4*)(Arow + (size_t)r * GAT_N);
    f32x4 av1 = *(const f32x4*)(Arow + (size_t)r * GAT_N + 256);
    const f32x4 s4 = scon[i0 + row];  // broadcast load
    const float F1 = rfl(s4[0]), F2 = rfl(s4[1]);
    const float ns = rfl(s4[2]), cc = rfl(s4[3]);

    float p[4];
#pragma unroll
    for (int e = 0; e < 4; ++e) {
      float psel = (t0[e] >= ns) ? E1a[e] * F1 : E2a[e] * F2;
      p[e] = (av0[e] > 0.f) ? psel : cc;
    }
    __hip_bfloat162 pa = __float22bfloat162_rn(float2{p[0], p[1]});
    __hip_bfloat162 pb = __float22bfloat162_rn(float2{p[2], p[3]});
    uint2 w;
    __builtin_memcpy(&w.x, &pa, 4);
    __builtin_memcpy(&w.y, &pb, 4);
    *(uint2*)(&smem[(row << 10) + ((lane << 3) ^ ((row & 7) << 4))]) = w;

#pragma unroll
    for (int e = 0; e < 4; ++e) {
      float psel = (t1[e] >= ns) ? E1b[e] * F1 : E2b[e] * F2;
      p[e] = (av1[e] > 0.f) ? psel : cc;
    }
    pa = __float22bfloat162_rn(float2{p[0], p[1]});
    pb = __float22bfloat162_rn(float2{p[2], p[3]});
    __builtin_memcpy(&w.x, &pa, 4);
    __builtin_memcpy(&w.y, &pb, 4);
    *(uint2*)(&smem[(row << 10) + ((512 + (lane << 3)) ^ ((row & 7) << 4))]) = w;
  }
  __syncthreads();  // P tile ready

  // ---- MFMA: wave wv owns k-quads {2wv, 2wv+1} ----
  bf16x8 ones;
#pragma unroll
  for (int e = 0; e < 8; ++e) ones[e] = (short)0x3F80;

  f32x4 acc[4][4];  // [dq][n] — fully unrolled -> static indices
  f32x4 accl[4];
#pragma unroll
  for (int dq = 0; dq < 4; ++dq)
#pragma unroll
    for (int n = 0; n < 4; ++n) acc[dq][n] = (f32x4){0.f, 0.f, 0.f, 0.f};
#pragma unroll
  for (int n = 0; n < 4; ++n) accl[n] = (f32x4){0.f, 0.f, 0.f, 0.f};

  const short* Wb = WhT_f + (size_t)jc * 32768 + lane * 8;
#pragma unroll
  for (int q = 0; q < 2; ++q) {
    const int kq = wv * 2 + q;
    bf16x8 bP[4];
#pragma unroll
    for (int n = 0; n < 4; ++n) {
      const int rr = n * 16 + rsub;
      const int raddr = (rr << 10) + (((kq << 6) | (kg << 4)) ^ ((rr & 7) << 4));
      bP[n] = *(const bf16x8*)(&smem[raddr]);
    }
#pragma unroll
    for (int dq = 0; dq < 4; ++dq) {
      bf16x8 a = *(const bf16x8*)(Wb + dq * 8192 + kq * 512);
#pragma unroll
      for (int n = 0; n < 4; ++n)
        acc[dq][n] = __builtin_amdgcn_mfma_f32_16x16x32_bf16(a, bP[n], acc[dq][n], 0, 0, 0);
    }
#pragma unroll
    for (int n = 0; n < 4; ++n)
      accl[n] = __builtin_amdgcn_mfma_f32_16x16x32_bf16(ones, bP[n], accl[n], 0, 0, 0);
  }
  __syncthreads();  // all P reads done before smem reuse

  // ---- two-stage combine (exact; fixed shift) ----
  // C/D layout (m89): col = lane&15 = n-sub (i); row = kg*4+reg = m-sub (d).
  float* lds_o = (float*)smem;            // [4][64][65]
  float* lds_l = (float*)(smem + 66560);  // [4][64]
  if (wv < 4) {
#pragma unroll
    for (int dq = 0; dq < 4; ++dq)
#pragma unroll
      for (int n = 0; n < 4; ++n)
#pragma unroll
        for (int r = 0; r < 4; ++r)
          lds_o[wv * 4160 + (n * 16 + rsub) * 65 + dq * 16 + kg * 4 + r] = acc[dq][n][r];
    if (kg == 0) {
#pragma unroll
      for (int n = 0; n < 4; ++n) lds_l[wv * 64 + n * 16 + rsub] = accl[n][0];
    }
  }
  __syncthreads();
  if (wv >= 4) {
    const int w2 = wv - 4;
#pragma unroll
    for (int dq = 0; dq < 4; ++dq)
#pragma unroll
      for (int n = 0; n < 4; ++n)
#pragma unroll
        for (int r = 0; r < 4; ++r)
          lds_o[w2 * 4160 + (n * 16 + rsub) * 65 + dq * 16 + kg * 4 + r] += acc[dq][n][r];
    if (kg == 0) {
#pragma unroll
      for (int n = 0; n < 4; ++n) lds_l[w2 * 64 + n * 16 + rsub] += accl[n][0];
    }
  }
  __syncthreads();

  float* opb = o_part + (size_t)jc * (GAT_N * 64) + (size_t)i0 * 64;
  for (int idx = tid; idx < 64 * 64; idx += 512) {
    const int ii = idx >> 6, d = idx & 63;
    float o = lds_o[0 * 4160 + ii * 65 + d] + lds_o[1 * 4160 + ii * 65 + d] +
              lds_o[2 * 4160 + ii * 65 + d] + lds_o[3 * 4160 + ii * 65 + d];
    opb[idx] = o;
    if (d == 0) {
      l_part[jc * GAT_N + i0 + ii] = lds_l[0 * 64 + ii] + lds_l[1 * 64 + ii] +
                                     lds_l[2 * 64 + ii] + lds_l[3 * 64 + ii];
    }
  }
}

// ---------------------------------------------------------------------------
// Kernel 3 (k_comb): exact merge of 16 j-chunk partials + ELU.
// ---------------------------------------------------------------------------
__global__ __launch_bounds__(256) void k_comb(const float* __restrict__ o_part,
                                              const float* __restrict__ l_part,
                                              float* __restrict__ out) {
  const int idx = blockIdx.x * 256 + threadIdx.x;  // one f32x4 of out
  const int gi = idx >> 4, d4 = (idx & 15) * 4;
  f32x4 o = {0.f, 0.f, 0.f, 0.f};
  float l = 0.f;
#pragma unroll
  for (int c = 0; c < 16; ++c) {
    o += *(const f32x4*)(o_part + (size_t)c * (GAT_N * 64) + (size_t)gi * 64 + d4);
    l += l_part[c * GAT_N + gi];
  }
  f32x4 v;
#pragma unroll
  for (int e = 0; e < 4; ++e) {
    float val = o[e] / l;
    v[e] = (val > 0.f) ? val : (__expf(val) - 1.f);
  }
  *(f32x4*)(out + (size_t)gi * GAT_D + d4) = v;
}

// ---------------------------------------------------------------------------
extern "C" void kernel_launch(void* const* d_in, const int* in_sizes, int n_in,
                              void* d_out, int out_size, void* d_ws, size_t ws_size,
                              hipStream_t stream) {
  const float* h = (const float*)d_in[0];
  const float* A = (const float*)d_in[1];
  const float* W = (const float*)d_in[2];
  const float* a = (const float*)d_in[3];
  float* out = (float*)d_out;

  // ws: [0,1K) bmax | [4K,+32K) s_src | [36864,+32K) s_dst | [69632,+1M) WhT_f
  //     [1572864,+512K) l_part | [2097152,+32M) o_part | [35651584,+128K) scon
  const size_t need = 35651584 + 131072;
  if (ws_size < need) return;
  float* bmax = (float*)d_ws;
  float* s_src = (float*)((char*)d_ws + 4096);
  float* s_dst = (float*)((char*)d_ws + 36864);
  short* WhT_f = (short*)((char*)d_ws + 69632);
  float* l_part = (float*)((char*)d_ws + 1572864);
  float* o_part = (float*)((char*)d_ws + 2097152);
  f32x4* scon = (f32x4*)((char*)d_ws + 35651584);

  k_prep<<<dim3(256), dim3(256), 0, stream>>>(h, W, a, s_src, s_dst, WhT_f, bmax);
  k_scon<<<dim3(GAT_N / 256), dim3(256), 0, stream>>>(s_src, bmax, scon);
  k_attn<<<dim3(2048), dim3(512), 0, stream>>>(A, s_dst, scon, WhT_f, o_part,
                                               l_part);
  k_comb<<<dim3(GAT_N * GAT_D / 1024), dim3(256), 0, stream>>>(o_part, l_part, out);
}

// Round 19
// 119.945 us; speedup vs baseline: 1.0342x; 1.0247x over previous
//
#include <hip/hip_runtime.h>
#include <hip/hip_bf16.h>

#define GAT_N 8192
#define GAT_K 256
#define GAT_D 64
#define GAT_ALPHA 0.2f
#define GAT_FILL 1e-15f

typedef float f32x4 __attribute__((ext_vector_type(4)));
typedef short bf16x8 __attribute__((ext_vector_type(8)));

static __device__ __forceinline__ unsigned f2bf_u(float x) {
  unsigned u = __float_as_uint(x);
  u += 0x7FFFu + ((u >> 16) & 1u);
  return u >> 16;
}

static __device__ __forceinline__ float rfl(float x) {
  return __uint_as_float(__builtin_amdgcn_readfirstlane(__float_as_uint(x)));
}

// ---------------------------------------------------------------------------
// Kernel 1: register-tiled Wh = h @ W; emits WhT_f in MFMA-fragment-tiled
// layout (validated rounds 15-18).
// ---------------------------------------------------------------------------
__global__ __launch_bounds__(256) void k_prep(const float* __restrict__ h,
                                              const float* __restrict__ W,
                                              const float* __restrict__ av,
                                              float* __restrict__ s_src,
                                              float* __restrict__ s_dst,
                                              short* __restrict__ WhT_f,
                                              float* __restrict__ bmax) {
  __shared__ short T[4][64][8];
  __shared__ float wmLds[4];
  const int tid = threadIdx.x;
  const int wv = tid >> 6, lane = tid & 63;
  const int r0 = blockIdx.x * 32 + wv * 8;  // 8 consecutive k (=j) indices

  float acc[8], acc2[8];
#pragma unroll
  for (int r = 0; r < 8; ++r) { acc[r] = 0.f; acc2[r] = 0.f; }

  for (int kc = 0; kc < GAT_K; kc += 32) {
    float Wreg[32];
#pragma unroll
    for (int e = 0; e < 32; ++e) Wreg[e] = W[(size_t)(kc + e) * GAT_D + lane];
#pragma unroll
    for (int r = 0; r < 8; ++r) {
      const f32x4* h4 = (const f32x4*)(h + (size_t)(r0 + r) * GAT_K + kc);
#pragma unroll
      for (int q = 0; q < 8; ++q) {
        f32x4 hv = h4[q];
        acc[r] += hv[0] * Wreg[4 * q + 0];
        acc2[r] += hv[1] * Wreg[4 * q + 1];
        acc[r] += hv[2] * Wreg[4 * q + 2];
        acc2[r] += hv[3] * Wreg[4 * q + 3];
      }
    }
  }

  const float a_s = av[lane];
  const float a_d = av[64 + lane];
  float wmax = -3.0e38f;
#pragma unroll
  for (int r = 0; r < 8; ++r) {
    const float accf = acc[r] + acc2[r];
    T[wv][lane][r] = (short)f2bf_u(accf);
    float vs = accf * a_s, vd = accf * a_d;
#pragma unroll
    for (int off = 32; off > 0; off >>= 1) {
      vs += __shfl_xor(vs, off);
      vd += __shfl_xor(vd, off);
    }
    if (lane == 0) { s_src[r0 + r] = vs; s_dst[r0 + r] = vd; }
    wmax = fmaxf(wmax, vd);
  }
  bf16x8 vt = *(const bf16x8*)&T[wv][lane][0];
  {
    const int c = r0 >> 9, f = (r0 & 511) >> 5, kgr = (r0 & 31) >> 3;
    short* dst = WhT_f + (size_t)c * 32768 + (size_t)(lane >> 4) * 8192 +
                 f * 512 + ((lane & 15) + 16 * kgr) * 8;
    *(bf16x8*)dst = vt;
  }

  if (lane == 0) wmLds[wv] = wmax;
  __syncthreads();
  if (tid == 0) {
    bmax[blockIdx.x] = fmaxf(fmaxf(wmLds[0], wmLds[1]), fmaxf(wmLds[2], wmLds[3]));
  }
}

// ---------------------------------------------------------------------------
// Kernel 1b (k_scon): per-row constants {F1, F2, -s, cc} (validated R18).
// ---------------------------------------------------------------------------
__global__ __launch_bounds__(256) void k_scon(const float* __restrict__ s_src,
                                              const float* __restrict__ bmax,
                                              f32x4* __restrict__ scon) {
  const int r = blockIdx.x * 256 + threadIdx.x;
  const int lane = threadIdx.x & 63;
  float bm = fmaxf(fmaxf(bmax[lane], bmax[lane + 64]),
                   fmaxf(bmax[lane + 128], bmax[lane + 192]));
#pragma unroll
  for (int off = 32; off > 0; off >>= 1) bm = fmaxf(bm, __shfl_xor(bm, off));
  const float tmax = bm;

  const float sc = s_src[r];
  const float x0 = sc + tmax;
  const float m = fmaxf(fmaxf(x0, GAT_ALPHA * x0), GAT_FILL);
  f32x4 s4;
  s4[0] = __expf(sc - m);
  s4[1] = __expf(GAT_ALPHA * sc - m);
  s4[2] = -sc;
  s4[3] = __expf(GAT_FILL - m);
  scon[r] = s4;
}

// ---------------------------------------------------------------------------
// Kernel 2 (k_attn): round-16 structure (BM=16, j-split one-shot blocks,
// 8192 blocks x 256 thr) with MAXIMIZED per-wave memory parallelism:
//   - launch_bounds(256,4): 128-VGPR cap, room to HOLD operands
//   - all 8 A-loads issued FIRST into named regs (8 KB in flight per wave)
//   - 16 WhT fragments issued BEFORE the barrier (hide under LDS writes)
//   - scon table: zero serial prologue
// ---------------------------------------------------------------------------
__global__ __launch_bounds__(256, 4) void k_attn(
    const float* __restrict__ A,
    const float* __restrict__ s_dst,
    const f32x4* __restrict__ scon,
    const short* __restrict__ WhT_f,
    float* __restrict__ o_part,
    float* __restrict__ l_part) {
  __shared__ char smem[16896];  // P tile [0,16K); reuse: lds_o[4][16][65] | lds_l @16640

  const int tid = threadIdx.x;
  const int wv = tid >> 6, lane = tid & 63;
  const int rsub = lane & 15, kg = lane >> 4;
  const int it = blockIdx.x >> 4, jc = blockIdx.x & 15;
  const int i0 = it * 16, j0 = jc * 512;

  // ---- issue ALL A-loads first: 8 x 1KB wave-loads in flight ----
  const float* Arow = A + (size_t)(i0 + 4 * wv) * GAT_N + j0 + lane * 4;
  f32x4 av0 = *(const f32x4*)(Arow + 0 * GAT_N);
  f32x4 av1 = *(const f32x4*)(Arow + 0 * GAT_N + 256);
  f32x4 av2 = *(const f32x4*)(Arow + 1 * GAT_N);
  f32x4 av3 = *(const f32x4*)(Arow + 1 * GAT_N + 256);
  f32x4 av4 = *(const f32x4*)(Arow + 2 * GAT_N);
  f32x4 av5 = *(const f32x4*)(Arow + 2 * GAT_N + 256);
  f32x4 av6 = *(const f32x4*)(Arow + 3 * GAT_N);
  f32x4 av7 = *(const f32x4*)(Arow + 3 * GAT_N + 256);

  const f32x4 t0 = *(const f32x4*)(s_dst + j0 + lane * 4);
  const f32x4 t1 = *(const f32x4*)(s_dst + j0 + 256 + lane * 4);
  const f32x4 sc0 = scon[i0 + 4 * wv + 0];
  const f32x4 sc1 = scon[i0 + 4 * wv + 1];
  const f32x4 sc2 = scon[i0 + 4 * wv + 2];
  const f32x4 sc3 = scon[i0 + 4 * wv + 3];

  f32x4 E1a, E2a, E1b, E2b;
#pragma unroll
  for (int e = 0; e < 4; ++e) {
    E1a[e] = __expf(t0[e]);
    E2a[e] = __expf(GAT_ALPHA * t0[e]);
    E1b[e] = __expf(t1[e]);
    E2b[e] = __expf(GAT_ALPHA * t1[e]);
  }

  auto stage = [&](int row, const f32x4& avA, const f32x4& avB, const f32x4& s4) {
    const float F1 = rfl(s4[0]), F2 = rfl(s4[1]);
    const float ns = rfl(s4[2]), cc = rfl(s4[3]);
    float p[4];
#pragma unroll
    for (int e = 0; e < 4; ++e) {
      float psel = (t0[e] >= ns) ? E1a[e] * F1 : E2a[e] * F2;
      p[e] = (avA[e] > 0.f) ? psel : cc;
    }
    __hip_bfloat162 pa = __float22bfloat162_rn(float2{p[0], p[1]});
    __hip_bfloat162 pb = __float22bfloat162_rn(float2{p[2], p[3]});
    uint2 w;
    __builtin_memcpy(&w.x, &pa, 4);
    __builtin_memcpy(&w.y, &pb, 4);
    *(uint2*)(&smem[(row << 10) + ((lane << 3) ^ ((row & 7) << 4))]) = w;

#pragma unroll
    for (int e = 0; e < 4; ++e) {
      float psel = (t1[e] >= ns) ? E1b[e] * F1 : E2b[e] * F2;
      p[e] = (avB[e] > 0.f) ? psel : cc;
    }
    pa = __float22bfloat162_rn(float2{p[0], p[1]});
    pb = __float22bfloat162_rn(float2{p[2], p[3]});
    __builtin_memcpy(&w.x, &pa, 4);
    __builtin_memcpy(&w.y, &pb, 4);
    *(uint2*)(&smem[(row << 10) + ((512 + (lane << 3)) ^ ((row & 7) << 4))]) = w;
  };

  stage(4 * wv + 0, av0, av1, sc0);
  stage(4 * wv + 1, av2, av3, sc1);
  stage(4 * wv + 2, av4, av5, sc2);
  stage(4 * wv + 3, av6, av7, sc3);

  // ---- issue WhT fragment loads BEFORE the barrier (hide their latency) ----
  const short* Wb = WhT_f + (size_t)jc * 32768 + lane * 8;
  bf16x8 wa[4][4];  // [q][dq], static indices
#pragma unroll
  for (int q = 0; q < 4; ++q) {
    const int kq = wv * 4 + q;
#pragma unroll
    for (int dq = 0; dq < 4; ++dq)
      wa[q][dq] = *(const bf16x8*)(Wb + dq * 8192 + kq * 512);
  }

  __syncthreads();  // P tile ready

  // ---- MFMA: wave wv owns k-quads 4wv..4wv+3 ----
  bf16x8 ones;
#pragma unroll
  for (int e = 0; e < 8; ++e) ones[e] = (short)0x3F80;

  f32x4 acc0 = {0.f, 0.f, 0.f, 0.f};
  f32x4 acc1 = {0.f, 0.f, 0.f, 0.f};
  f32x4 acc2 = {0.f, 0.f, 0.f, 0.f};
  f32x4 acc3 = {0.f, 0.f, 0.f, 0.f};
  f32x4 accl = {0.f, 0.f, 0.f, 0.f};

#pragma unroll
  for (int q = 0; q < 4; ++q) {
    const int kq = wv * 4 + q;
    const int raddr = (rsub << 10) + (((kq << 6) | (kg << 4)) ^ ((rsub & 7) << 4));
    bf16x8 bP = *(const bf16x8*)(&smem[raddr]);  // B-op: P[k][n=i]
    acc0 = __builtin_amdgcn_mfma_f32_16x16x32_bf16(wa[q][0], bP, acc0, 0, 0, 0);
    acc1 = __builtin_amdgcn_mfma_f32_16x16x32_bf16(wa[q][1], bP, acc1, 0, 0, 0);
    acc2 = __builtin_amdgcn_mfma_f32_16x16x32_bf16(wa[q][2], bP, acc2, 0, 0, 0);
    acc3 = __builtin_amdgcn_mfma_f32_16x16x32_bf16(wa[q][3], bP, acc3, 0, 0, 0);
    accl = __builtin_amdgcn_mfma_f32_16x16x32_bf16(ones, bP, accl, 0, 0, 0);
  }
  __syncthreads();  // all P reads done before smem reuse

  // ---- combine 4 wave-partials (exact; fixed shift) -> o_part ----
  // C/D layout (m89): col = lane&15 = n = i-sub; row = kg*4+reg = m = d-sub.
  float* lds_o = (float*)smem;            // [4][16][65]
  float* lds_l = (float*)(smem + 16640);  // [4][16]
#pragma unroll
  for (int r = 0; r < 4; ++r) {
    const int d = kg * 4 + r;
    lds_o[wv * 1040 + rsub * 65 + 0 * 16 + d] = acc0[r];
    lds_o[wv * 1040 + rsub * 65 + 1 * 16 + d] = acc1[r];
    lds_o[wv * 1040 + rsub * 65 + 2 * 16 + d] = acc2[r];
    lds_o[wv * 1040 + rsub * 65 + 3 * 16 + d] = acc3[r];
  }
  if (kg == 0) lds_l[wv * 16 + rsub] = accl[0];
  __syncthreads();

  float* opb = o_part + ((size_t)jc * 512 + it) * 1024;
  for (int idx = tid; idx < 1024; idx += 256) {
    const int ii = idx >> 6, d = idx & 63;
    float o = lds_o[0 * 1040 + ii * 65 + d] + lds_o[1 * 1040 + ii * 65 + d] +
              lds_o[2 * 1040 + ii * 65 + d] + lds_o[3 * 1040 + ii * 65 + d];
    opb[idx] = o;
    if (d == 0) {
      l_part[jc * GAT_N + i0 + ii] = lds_l[0 * 16 + ii] + lds_l[1 * 16 + ii] +
                                     lds_l[2 * 16 + ii] + lds_l[3 * 16 + ii];
    }
  }
}

// ---------------------------------------------------------------------------
// Kernel 3 (k_comb): exact merge of 16 j-chunk partials + ELU.
// ---------------------------------------------------------------------------
__global__ __launch_bounds__(256) void k_comb(const float* __restrict__ o_part,
                                              const float* __restrict__ l_part,
                                              float* __restrict__ out) {
  const int idx = blockIdx.x * 256 + threadIdx.x;  // one f32x4 of out
  const int gi = idx >> 4, d4 = (idx & 15) * 4;
  const int it = gi >> 4, ii = gi & 15;
  f32x4 o = {0.f, 0.f, 0.f, 0.f};
  float l = 0.f;
#pragma unroll
  for (int c = 0; c < 16; ++c) {
    o += *(const f32x4*)(o_part + ((size_t)c * 512 + it) * 1024 + ii * 64 + d4);
    l += l_part[c * GAT_N + gi];
  }
  f32x4 v;
#pragma unroll
  for (int e = 0; e < 4; ++e) {
    float val = o[e] / l;
    v[e] = (val > 0.f) ? val : (__expf(val) - 1.f);
  }
  *(f32x4*)(out + (size_t)gi * GAT_D + d4) = v;
}

// ---------------------------------------------------------------------------
extern "C" void kernel_launch(void* const* d_in, const int* in_sizes, int n_in,
                              void* d_out, int out_size, void* d_ws, size_t ws_size,
                              hipStream_t stream) {
  const float* h = (const float*)d_in[0];
  const float* A = (const float*)d_in[1];
  const float* W = (const float*)d_in[2];
  const float* a = (const float*)d_in[3];
  float* out = (float*)d_out;

  // ws: [0,1K) bmax | [4K,+32K) s_src | [36864,+32K) s_dst | [69632,+1M) WhT_f
  //     [1572864,+512K) l_part | [2097152,+32M) o_part | [35651584,+128K) scon
  const size_t need = 35651584 + 131072;
  if (ws_size < need) return;
  float* bmax = (float*)d_ws;
  float* s_src = (float*)((char*)d_ws + 4096);
  float* s_dst = (float*)((char*)d_ws + 36864);
  short* WhT_f = (short*)((char*)d_ws + 69632);
  float* l_part = (float*)((char*)d_ws + 1572864);
  float* o_part = (float*)((char*)d_ws + 2097152);
  f32x4* scon = (f32x4*)((char*)d_ws + 35651584);

  k_prep<<<dim3(256), dim3(256), 0, stream>>>(h, W, a, s_src, s_dst, WhT_f, bmax);
  k_scon<<<dim3(GAT_N / 256), dim3(256), 0, stream>>>(s_src, bmax, scon);
  k_attn<<<dim3(8192), dim3(256), 0, stream>>>(A, s_dst, scon, WhT_f, o_part,
                                               l_part);
  k_comb<<<dim3(GAT_N * GAT_D / 1024), dim3(256), 0, stream>>>(o_part, l_part, out);
}